// Round 13
// baseline (123.830 us; speedup 1.0000x reference)
//
#include <hip/hip_runtime.h>
#include <math.h>

#define S_ 2048
#define NH 8
#define LP 72         // bf16 LDS row pitch: 144 B = 9*16 B -> b128-aligned
#define RP 328        // R_lds pitch (bf16): 656 B rows

typedef __attribute__((ext_vector_type(8))) short short8;   // 8 x bf16 (4 VGPRs)
typedef __attribute__((ext_vector_type(4))) float f32x4;    // MFMA accumulator
typedef unsigned short ushort_t;

__device__ __forceinline__ short bf16r(float x) {   // RNE float->bf16
    union { float f; unsigned u; } v; v.f = x;
    unsigned r = v.u + 0x7fffu + ((v.u >> 16) & 1u);
    return (short)(r >> 16);
}
__device__ __forceinline__ float b2f(ushort_t h) {  // bf16->float
    union { float f; unsigned u; } v; v.u = ((unsigned)h) << 16; return v.f;
}

// ---------------------------------------------------------------------------
// Kernel 0: prep.  z<4: WT[n][k] = bf16(W[k][n]) (LDS-tiled 64x64).
// z==4: pos table bf16; rows 257..383 zero.
// z==5: FUSED xb16 = bf16(x) + xpart column partial sums (single x pass;
//       the old separate z==6 colsum re-read 16 MB of x).
// ---------------------------------------------------------------------------
__global__ __launch_bounds__(256) void prep_kernel(
    const float* __restrict__ x,
    const float* __restrict__ Wq, const float* __restrict__ Wk,
    const float* __restrict__ Wv, const float* __restrict__ Wkr,
    ushort_t* __restrict__ WTq, ushort_t* __restrict__ WTk,
    ushort_t* __restrict__ WTv, ushort_t* __restrict__ WTkr,
    ushort_t* __restrict__ pos, ushort_t* __restrict__ xb16,
    float* __restrict__ xpart)
{
    const int widx = blockIdx.z;
    const int t = threadIdx.x;

    __shared__ __align__(16) ushort_t T[64][72];      // transpose tile
    __shared__ __align__(16) float red[8][512];       // z5 colsum reduce

    if (widx == 4) {
        const int base = blockIdx.y * 8 + blockIdx.x;    // 0..63
        const float C = -0.051905126482615036f;          // -log2(10000)/256
        const int f = t;
#pragma unroll
        for (int rep = 0; rep < 6; ++rep) {
            const int r = base + rep * 64;               // 0..383
            unsigned pk = 0;
            if (r <= 256) {
                float ang = (float)r * exp2f(C * (float)f);
                unsigned s = (unsigned)(ushort_t)bf16r(sinf(ang));
                unsigned c = (unsigned)(ushort_t)bf16r(cosf(ang));
                pk = s | (c << 16);
            }
            ((unsigned*)pos)[(size_t)r * 256 + f] = pk;
        }
        return;
    }
    if (widx == 5) {
        // fused convert + column partial sums over this 64-row stripe
        const int sub = blockIdx.y * 8 + blockIdx.x;     // 0..63
        const size_t base = (size_t)sub * 32768;
        float csum[16];
#pragma unroll
        for (int u = 0; u < 16; ++u) csum[u] = 0.f;
#pragma unroll
        for (int it = 0; it < 8; ++it) {
            const size_t idx = base + (size_t)it * 4096 + (size_t)t * 16;
            const float* src = &x[idx];
            ushort_t t16[16];
#pragma unroll
            for (int u = 0; u < 16; ++u) {
                const float f = src[u];
                t16[u] = (ushort_t)bf16r(f);
                csum[u] += f;
            }
            *(short8*)&xb16[idx]     = *(short8*)&t16[0];
            *(short8*)&xb16[idx + 8] = *(short8*)&t16[8];
        }
        // thread t covered rows {it*8 + (t>>5)}, cols (t&31)*16..+15
        {
            const int g = t >> 5, c0 = (t & 31) * 16;
#pragma unroll
            for (int u = 0; u < 16; ++u) red[g][c0 + u] = csum[u];
        }
        __syncthreads();
#pragma unroll
        for (int c = t; c < 512; c += 256) {
            float s = 0.f;
#pragma unroll
            for (int g = 0; g < 8; ++g) s += red[g][c];
            xpart[(size_t)sub * 512 + c] = s;
        }
        return;
    }
    const float* W = (widx == 0) ? Wq : (widx == 1) ? Wk : (widx == 2) ? Wv : Wkr;
    ushort_t* WT   = (widx == 0) ? WTq : (widx == 1) ? WTk : (widx == 2) ? WTv : WTkr;
    const int k0 = blockIdx.x * 64, n0 = blockIdx.y * 64;
    const int srow = t >> 2, sc0 = (t & 3) * 16;
    const float* src = &W[(size_t)(k0 + srow) * 512 + n0 + sc0];
#pragma unroll
    for (int u = 0; u < 16; ++u) T[sc0 + u][srow] = (ushort_t)bf16r(src[u]);
    __syncthreads();
    ushort_t* dst = &WT[(size_t)(n0 + srow) * 512 + k0 + sc0];
    *(short8*)dst       = *(const short8*)&T[srow][sc0];
    *(short8*)(dst + 8) = *(const short8*)&T[srow][sc0 + 8];
}

// ---------------------------------------------------------------------------
// Kernel 1: fused QKV (+krel +vmean) GEMM.  Grid (32, 25).  (byte-identical
// to R12: double-buffered LDS, xlen elision on q/k/vT, vmean from xpart.)
// ---------------------------------------------------------------------------
__global__ __launch_bounds__(256) void qkv_gemm(
    const ushort_t* __restrict__ xb16,
    const ushort_t* __restrict__ WTq, const ushort_t* __restrict__ WTk,
    const ushort_t* __restrict__ WTv,
    const ushort_t* __restrict__ pos, const ushort_t* __restrict__ WTkr,
    const float* __restrict__ b_con, const float* __restrict__ b_rel,
    const float* __restrict__ bv, const int* __restrict__ xlen_p,
    const float* __restrict__ xpart,
    ushort_t* __restrict__ qcon, ushort_t* __restrict__ qrel,
    ushort_t* __restrict__ kout, ushort_t* __restrict__ vT,
    ushort_t* __restrict__ krel, float* __restrict__ vmean)
{
    const int widx = blockIdx.y >> 3;
    const int tid = threadIdx.x, lane = tid & 63, w = tid >> 6;
    const int quad = lane >> 4, l16 = lane & 15;

    __shared__ __align__(16) ushort_t A_lds[2][128][40];
    __shared__ __align__(16) ushort_t B_lds[2][64][40];

    f32x4 acc[2][4];
#pragma unroll
    for (int mt = 0; mt < 2; ++mt)
#pragma unroll
        for (int nt = 0; nt < 4; ++nt) acc[mt][nt] = (f32x4){0.f, 0.f, 0.f, 0.f};

    const int arow = tid >> 1, ak0 = (tid & 1) * 16;
    const int brow = tid >> 2, bk0 = (tid & 3) * 8;

    const ushort_t* Asrc;          // per-mode A row pointer (128 rows x 512)
    const ushort_t* Bsrc;          // per-mode B row pointer (64 rows x 512)

    if (widx < 2) {
        const int m0 = blockIdx.x * 128;
        {
            const int xl = xlen_p[m0 >> 11];
            const int s0 = m0 & 2047;
            if (widx == 0) { if (s0 >= xl + 256) return; }   // q rows dead
            else           { if (s0 >= xl + 63)  return; }   // k rows never staged
        }
        const int n0 = (blockIdx.y & 7) * 64;
        const ushort_t* WT = (widx == 0) ? WTq : WTk;
        Asrc = &xb16[(size_t)(m0 + arow) * 512 + ak0];
        Bsrc = &WT[(size_t)(n0 + brow) * 512 + bk0];
    } else if (widx == 2) {
        const int vb = (blockIdx.y & 7) * 32 + blockIdx.x;   // 0..255
        const int m0d = (vb & 3) * 128;
        const int n0j = (vb >> 2) * 64;
        {
            // attn reads vT cols j <= xlen+62 only; vmean is x-based
            const int xl = xlen_p[n0j >> 11];
            if ((n0j & 2047) >= xl + 63) return;
        }
        Asrc = &WTv[(size_t)(m0d + arow) * 512 + ak0];
        Bsrc = &xb16[(size_t)(n0j + brow) * 512 + bk0];
    } else {
        if (blockIdx.x >= 24) {
            // ---- vmean: vmean[b][d] = mean_x[b] . WTv[d] + bv[d] ----
            float* xm = (float*)A_lds;                       // [2][512] fp32
            for (int idx = tid; idx < 1024; idx += 256) {
                const int bb = idx >> 9, k = idx & 511;
                float s = 0.f;
                for (int p = 0; p < 32; ++p)
                    s += xpart[(size_t)(bb * 32 + p) * 512 + k];
                xm[bb * 512 + k] = s * (1.0f / 2048.0f);
            }
            __syncthreads();
            if (tid < 64) {
                const int d = (blockIdx.x - 24) * 64 + tid;
                const ushort_t* wrow = &WTv[(size_t)d * 512];
                float a0 = 0.f, a1 = 0.f;
                for (int k = 0; k < 512; k += 8) {
                    short8 wv = *(const short8*)(wrow + k);
#pragma unroll
                    for (int u = 0; u < 8; ++u) {
                        const float wf = b2f((ushort_t)wv[u]);
                        a0 += xm[k + u] * wf;
                        a1 += xm[512 + k + u] * wf;
                    }
                }
                const float bvd = bv[d];
                vmean[d]       = a0 + bvd;
                vmean[512 + d] = a1 + bvd;
            }
            return;
        }
        const int m0 = (blockIdx.x >> 3) * 128;
        const int n0 = (blockIdx.x & 7) * 64;
        Asrc = &pos[(size_t)(m0 + arow) * 512 + ak0];
        Bsrc = &WTkr[(size_t)(n0 + brow) * 512 + bk0];
    }

    // ---- shared double-buffered K-loop (identical math order to R6/R9) ----
    {
        short8 pa0 = *(const short8*)Asrc;
        short8 pa1 = *(const short8*)(Asrc + 8);
        short8 pb  = *(const short8*)Bsrc;
        *(short8*)&A_lds[0][arow][ak0]     = pa0;
        *(short8*)&A_lds[0][arow][ak0 + 8] = pa1;
        *(short8*)&B_lds[0][brow][bk0]     = pb;
        pa0 = *(const short8*)(Asrc + 32);
        pa1 = *(const short8*)(Asrc + 40);
        pb  = *(const short8*)(Bsrc + 32);
        __syncthreads();

#pragma unroll 1
        for (int it = 0; it < 16; ++it) {
            const int cur = it & 1;
            if (it < 15) {
                *(short8*)&A_lds[cur ^ 1][arow][ak0]     = pa0;
                *(short8*)&A_lds[cur ^ 1][arow][ak0 + 8] = pa1;
                *(short8*)&B_lds[cur ^ 1][brow][bk0]     = pb;
                if (it < 14) {
                    pa0 = *(const short8*)(Asrc + it * 32 + 64);
                    pa1 = *(const short8*)(Asrc + it * 32 + 72);
                    pb  = *(const short8*)(Bsrc + it * 32 + 64);
                }
            }
            short8 a0 = *(const short8*)&A_lds[cur][w * 32 + l16][quad * 8];
            short8 a1 = *(const short8*)&A_lds[cur][w * 32 + 16 + l16][quad * 8];
#pragma unroll
            for (int nt = 0; nt < 4; ++nt) {
                short8 bb = *(const short8*)&B_lds[cur][nt * 16 + l16][quad * 8];
                acc[0][nt] = __builtin_amdgcn_mfma_f32_16x16x32_bf16(a0, bb, acc[0][nt], 0, 0, 0);
                acc[1][nt] = __builtin_amdgcn_mfma_f32_16x16x32_bf16(a1, bb, acc[1][nt], 0, 0, 0);
            }
            __syncthreads();
        }
    }

    // ---- epilogues ----
    if (widx < 2) {
        const int m0 = blockIdx.x * 128;
        const int n0 = (blockIdx.y & 7) * 64;
#pragma unroll
        for (int nt = 0; nt < 4; ++nt) {
            const int col = n0 + nt * 16 + l16;
            float bc = 0.f, br = 0.f;
            if (widx == 0) { bc = b_con[col]; br = b_rel[col]; }
#pragma unroll
            for (int mt = 0; mt < 2; ++mt) {
#pragma unroll
                for (int reg = 0; reg < 4; ++reg) {
                    const size_t m = (size_t)(m0 + w * 32 + mt * 16 + quad * 4 + reg);
                    const float val = acc[mt][nt][reg];
                    if (widx == 0) {
                        qcon[m * 512 + col] = (ushort_t)bf16r((val + bc) * 0.125f);
                        qrel[m * 512 + col] = (ushort_t)bf16r((val + br) * 0.125f);
                    } else {
                        kout[m * 512 + col] = (ushort_t)bf16r(val);
                    }
                }
            }
        }
    } else if (widx == 2) {
        const int vb = (blockIdx.y & 7) * 32 + blockIdx.x;
        const int m0d = (vb & 3) * 128;
        const int n0j = (vb >> 2) * 64;
        const int b = n0j >> 11;
#pragma unroll
        for (int mt = 0; mt < 2; ++mt) {
#pragma unroll
            for (int reg = 0; reg < 4; ++reg) {
                const int d = m0d + w * 32 + mt * 16 + quad * 4 + reg;  // 0..511
                const int n = d >> 6, dd = d & 63;
                const float bvv = bv[d];
#pragma unroll
                for (int nt = 0; nt < 4; ++nt) {
                    const int s = (n0j + nt * 16 + l16) & 2047;
                    vT[((size_t)((b * NH + n) * 64 + dd)) * 2048 + s] =
                        (ushort_t)bf16r(acc[mt][nt][reg] + bvv);
                }
            }
        }
    } else {
        const int m0 = (blockIdx.x >> 3) * 128;
        const int n0 = (blockIdx.x & 7) * 64;
#pragma unroll
        for (int nt = 0; nt < 4; ++nt) {
            const int col = n0 + nt * 16 + l16;
#pragma unroll
            for (int mt = 0; mt < 2; ++mt)
#pragma unroll
                for (int reg = 0; reg < 4; ++reg) {
                    const size_t m = (size_t)(m0 + w * 32 + mt * 16 + quad * 4 + reg);
                    krel[m * 512 + col] = (ushort_t)bf16r(acc[mt][nt][reg]);
                }
        }
    }
}

// ---------------------------------------------------------------------------
// Kernel 2: banded attention with fused rel-energy.  R12 structure, plus:
// RG phase now single-barrier double-buffered (krel staging alternates
// between the two 9 KB kv_lds halves; next chunk's loads prefetched before
// the barrier).  Main loop unchanged.  LDS 60.4 KB -> 2 blocks/CU.
// ---------------------------------------------------------------------------
__global__ __launch_bounds__(256) void attn_kernel(
    const ushort_t* __restrict__ qcon, const ushort_t* __restrict__ qrel,
    const ushort_t* __restrict__ kbuf, const ushort_t* __restrict__ vT,
    const ushort_t* __restrict__ krel, const float* __restrict__ vmean,
    const int* __restrict__ xlen_p, float* __restrict__ out)
{
    const int bx = blockIdx.x;
    const int tile = ((bx & 7) << 2) | (bx >> 3);   // XCD swizzle, 32 tiles
    const int n = blockIdx.y, b = blockIdx.z;
    const int i0 = tile * 64;
    const int tid = threadIdx.x, lane = tid & 63, w = tid >> 6;
    const int quad = lane >> 4, l16 = lane & 15;
    const int xlen = xlen_p[b];

    // ---- dead-tile fast path: every row fully masked -> uniform softmax ----
    if (i0 >= xlen + 256) {
        const int row = tid >> 2, cf = (tid & 3) * 16;
        const float* vm = &vmean[(size_t)b * 512 + n * 64 + cf];
        float* dst = &out[((size_t)b * S_ + i0 + row) * 512 + n * 64 + cf];
#pragma unroll
        for (int u = 0; u < 16; u += 4)
            *(float4*)&dst[u] = *(const float4*)&vm[u];
        return;
    }
    int nchunk = (xlen - i0 + 256 + 63) >> 6;
    if (nchunk > 5) nchunk = 5;
    const int c0 = (i0 < 256) ? ((256 - i0) >> 6) : 0;   // first chunk with jc0 >= 0

    __shared__ __align__(16) ushort_t kv_lds[2][64][LP]; // [0]=k, [1]=vT (main)
    __shared__ __align__(16) ushort_t R_lds[64][RP];     // R panel, overlaid by p

    ushort_t (*k_lds)[LP]  = kv_lds[0];
    ushort_t (*vT_lds)[LP] = kv_lds[1];

    const int srow = tid >> 2, sc0 = (tid & 3) * 16;     // 64 rows x 64 cols staging
    const size_t vTbase = (size_t)((b * NH + n) * 64) * 2048;

    short8 kr[2], vr[2], kn[2], vn[2];

    auto issue = [&](int c, short8* kd, short8* vd) {
        const int jc0 = i0 - 256 + c * 64;              // >= 0 for c >= c0
        const ushort_t* ks = &kbuf[((size_t)b * S_ + jc0 + srow) * 512 + n * 64 + sc0];
        kd[0] = *(const short8*)ks;
        kd[1] = *(const short8*)(ks + 8);
        const ushort_t* vs = &vT[vTbase + (size_t)srow * 2048 + jc0 + sc0];
        vd[0] = *(const short8*)vs;
        vd[1] = *(const short8*)(vs + 8);
    };

    // ---- hoisted prefetches: independent of RG; latency hides under RG ----
    const ushort_t* qc = &qcon[((size_t)b * S_ + i0 + w * 16 + l16) * 512 + n * 64 + quad * 8];
    const short8 aq0 = *(const short8*)qc;
    const short8 aq1 = *(const short8*)(qc + 32);
    issue(c0, kr, vr);

    // ---- RG phase: R_lds[row][row+256-r] = qrel[i0+row] . krel[r] ----
    // single-barrier double-buffer across kv_lds halves + load pipelining
    {
        const ushort_t* qr = &qrel[((size_t)b * S_ + i0 + w * 16 + l16) * 512 + n * 64 + quad * 8];
        const short8 ar0 = *(const short8*)qr;
        const short8 ar1 = *(const short8*)(qr + 32);
        const int rlim = (i0 + 63 < 256) ? i0 + 63 : 256;   // max live r
        const int rcmax = rlim >> 6;
        auto kload = [&](int rc, short8& a, short8& c) {
            const ushort_t* ks = &krel[(size_t)(rc * 64 + srow) * 512 + n * 64 + sc0];
            a = *(const short8*)ks;
            c = *(const short8*)(ks + 8);
        };
        short8 cv0, cv1, nv0, nv1;
        kload(0, cv0, cv1);
#pragma unroll 1
        for (int rc = 0; rc <= rcmax; ++rc) {
            ushort_t (*buf)[LP] = kv_lds[rc & 1];
            *(short8*)&buf[srow][sc0]     = cv0;
            *(short8*)&buf[srow][sc0 + 8] = cv1;
            if (rc < rcmax) kload(rc + 1, nv0, nv1);
            __syncthreads();    // write(buf) done; reads of buf from rc-2
                                // finished before the rc-1 barrier
#pragma unroll
            for (int nt = 0; nt < 4; ++nt) {
                if (rc * 64 + nt * 16 <= rlim) {           // block-uniform
                    short8 b0 = *(const short8*)&buf[nt * 16 + l16][quad * 8];
                    short8 b1 = *(const short8*)&buf[nt * 16 + l16][quad * 8 + 32];
                    f32x4 s = (f32x4){0.f, 0.f, 0.f, 0.f};
                    s = __builtin_amdgcn_mfma_f32_16x16x32_bf16(ar0, b0, s, 0, 0, 0);
                    s = __builtin_amdgcn_mfma_f32_16x16x32_bf16(ar1, b1, s, 0, 0, 0);
                    const int r = rc * 64 + nt * 16 + l16;
#pragma unroll
                    for (int reg = 0; reg < 4; ++reg) {
                        const int rowq = w * 16 + quad * 4 + reg;   // wave-local
                        if (r <= 256) R_lds[rowq][rowq + 256 - r] = (ushort_t)bf16r(s[reg]);
                    }
                }
            }
            cv0 = nv0; cv1 = nv1;
        }
    }

    f32x4 Oa[4];
#pragma unroll
    for (int nt = 0; nt < 4; ++nt) Oa[nt] = (f32x4){0.f, 0.f, 0.f, 0.f};
    float lpart[4] = {};

#pragma unroll 1
    for (int c = c0; c < nchunk; ++c) {
        const int jc0 = i0 - 256 + c * 64;
        __syncthreads();   // prev-chunk reads of k/vT done (RG's kv reads on c==c0)
        *(short8*)&k_lds[srow][sc0]      = kr[0];
        *(short8*)&k_lds[srow][sc0 + 8]  = kr[1];
        *(short8*)&vT_lds[srow][sc0]     = vr[0];
        *(short8*)&vT_lds[srow][sc0 + 8] = vr[1];
        if (c + 1 < nchunk) issue(c + 1, kn, vn);
        __syncthreads();

        // ---- QK ----
        f32x4 Sacc[4];
#pragma unroll
        for (int jt = 0; jt < 4; ++jt) {
            short8 bk0 = *(const short8*)&k_lds[jt * 16 + l16][quad * 8];
            short8 bk1 = *(const short8*)&k_lds[jt * 16 + l16][quad * 8 + 32];
            f32x4 s = (f32x4){0.f, 0.f, 0.f, 0.f};
            s = __builtin_amdgcn_mfma_f32_16x16x32_bf16(aq0, bk0, s, 0, 0, 0);
            s = __builtin_amdgcn_mfma_f32_16x16x32_bf16(aq1, bk1, s, 0, 0, 0);
            Sacc[jt] = s;
        }

        // ---- mask + rel bias + exp; p overwrites R_lds slot (wave-local) ----
#pragma unroll
        for (int jt = 0; jt < 4; ++jt) {
#pragma unroll
            for (int reg = 0; reg < 4; ++reg) {
                const int row = w * 16 + quad * 4 + reg;
                const int i = i0 + row;
                const int j = jc0 + jt * 16 + l16;
                const int r = i - j;
                const bool valid = (j < xlen) && (r >= 0) && (r <= 256);
                float rvv = b2f(R_lds[row][c * 64 + jt * 16 + l16]);
                float e = valid ? __expf(Sacc[jt][reg] + rvv) : 0.f;
                lpart[reg] += e;
                R_lds[row][c * 64 + jt * 16 + l16] = (ushort_t)bf16r(e);
            }
        }
        // no barrier: p rows are wave-local (written+read by the same wave)

        // ---- PV (p read from R_lds overlay) ----
        short8 ap0 = *(const short8*)&R_lds[w * 16 + l16][c * 64 + quad * 8];
        short8 ap1 = *(const short8*)&R_lds[w * 16 + l16][c * 64 + quad * 8 + 32];
#pragma unroll
        for (int nt = 0; nt < 4; ++nt) {
            short8 bv0 = *(const short8*)&vT_lds[nt * 16 + l16][quad * 8];
            short8 bv1 = *(const short8*)&vT_lds[nt * 16 + l16][quad * 8 + 32];
            Oa[nt] = __builtin_amdgcn_mfma_f32_16x16x32_bf16(ap0, bv0, Oa[nt], 0, 0, 0);
            Oa[nt] = __builtin_amdgcn_mfma_f32_16x16x32_bf16(ap1, bv1, Oa[nt], 0, 0, 0);
        }

        // ---- rotate register sets ----
        kr[0] = kn[0]; kr[1] = kn[1];
        vr[0] = vn[0]; vr[1] = vn[1];
    }

#pragma unroll
    for (int reg = 0; reg < 4; ++reg) {
#pragma unroll
        for (int off = 1; off < 16; off <<= 1)
            lpart[reg] += __shfl_xor(lpart[reg], off, 64);
    }

#pragma unroll
    for (int reg = 0; reg < 4; ++reg) {
        const int i = i0 + w * 16 + quad * 4 + reg;
        const bool dead = (i >= xlen + 256);
        const float linv = 1.0f / lpart[reg];
#pragma unroll
        for (int nt = 0; nt < 4; ++nt) {
            const int d = n * 64 + nt * 16 + l16;
            float val = dead ? vmean[(size_t)b * 512 + d] : Oa[nt][reg] * linv;
            out[((size_t)b * S_ + i) * 512 + d] = val;
        }
    }
}

// ---------------------------------------------------------------------------
extern "C" void kernel_launch(void* const* d_in, const int* in_sizes, int n_in,
                              void* d_out, int out_size, void* d_ws, size_t ws_size,
                              hipStream_t stream) {
    const float* x     = (const float*)d_in[0];
    const float* Wq    = (const float*)d_in[1];
    const float* b_con = (const float*)d_in[2];
    const float* b_rel = (const float*)d_in[3];
    const float* Wk    = (const float*)d_in[4];
    const float* Wkr   = (const float*)d_in[5];
    const float* Wv    = (const float*)d_in[6];
    const float* bv    = (const float*)d_in[7];
    const int*   xlen  = (const int*)d_in[8];
    float* out = (float*)d_out;

    float* ws = (float*)d_ws;
    float* vmean = ws;                       // 1024 fp32
    float* xpart = vmean + 1024;             // 64*512 fp32
    ushort_t* ub   = (ushort_t*)(xpart + 32768);
    ushort_t* qcon = ub;                     // 2048*2*512 bf16 each
    ushort_t* kbuf = qcon + 2097152;
    ushort_t* vT   = kbuf + 2097152;         // 1024 x 2048 bf16
    ushort_t* qrel = vT   + 2097152;
    ushort_t* xb16 = qrel + 2097152;         // 4096*512 bf16
    ushort_t* krel = xb16 + 2097152;         // 384*512 bf16
    ushort_t* pos  = krel + 196608;          // 384*512 bf16
    ushort_t* WTq  = pos  + 196608;          // 512*512 bf16 each
    ushort_t* WTk  = WTq + 262144;
    ushort_t* WTv  = WTk + 262144;
    ushort_t* WTkr = WTv + 262144;

    prep_kernel<<<dim3(8, 8, 6), 256, 0, stream>>>(x, Wq, Wk, Wv, Wkr,
                                                   WTq, WTk, WTv, WTkr, pos, xb16,
                                                   xpart);
    qkv_gemm<<<dim3(32, 25), 256, 0, stream>>>(xb16, WTq, WTk, WTv, pos, WTkr,
                                               b_con, b_rel, bv, xlen, xpart,
                                               qcon, qrel, kbuf, vT, krel, vmean);
    attn_kernel<<<dim3(32, 8, 2), 256, 0, stream>>>(qcon, qrel, kbuf, vT, krel,
                                                    vmean, xlen, out);
}

// Round 14
// 120.634 us; speedup vs baseline: 1.0265x; 1.0265x over previous
//
#include <hip/hip_runtime.h>
#include <math.h>

#define S_ 2048
#define NH 8
#define LP 72         // bf16 LDS row pitch: 144 B = 9*16 B -> b128-aligned
#define RP 328        // R_lds pitch (bf16): 656 B rows

typedef __attribute__((ext_vector_type(8))) short short8;   // 8 x bf16 (4 VGPRs)
typedef __attribute__((ext_vector_type(4))) float f32x4;    // MFMA accumulator
typedef unsigned short ushort_t;

__device__ __forceinline__ short bf16r(float x) {   // RNE float->bf16
    union { float f; unsigned u; } v; v.f = x;
    unsigned r = v.u + 0x7fffu + ((v.u >> 16) & 1u);
    return (short)(r >> 16);
}
__device__ __forceinline__ float b2f(ushort_t h) {  // bf16->float
    union { float f; unsigned u; } v; v.u = ((unsigned)h) << 16; return v.f;
}

// ---------------------------------------------------------------------------
// Kernel 0: prep.  z<4: WT[n][k] = bf16(W[k][n]) (LDS-tiled 64x64).
// z==4: pos table bf16; rows 257..383 zero.  z==5: xb16 = bf16(x), xlen-
// elided (rows >= xl+383 never read by q/k/vT modes).  z==6: xpart column
// partial sums of x (for vmean-from-x; needs ALL rows -> no elision).
// ---------------------------------------------------------------------------
__global__ __launch_bounds__(256) void prep_kernel(
    const float* __restrict__ x,
    const float* __restrict__ Wq, const float* __restrict__ Wk,
    const float* __restrict__ Wv, const float* __restrict__ Wkr,
    const int* __restrict__ xlen_p,
    ushort_t* __restrict__ WTq, ushort_t* __restrict__ WTk,
    ushort_t* __restrict__ WTv, ushort_t* __restrict__ WTkr,
    ushort_t* __restrict__ pos, ushort_t* __restrict__ xb16,
    float* __restrict__ xpart)
{
    const int widx = blockIdx.z;
    const int t = threadIdx.x;
    if (widx == 4) {
        const int base = blockIdx.y * 8 + blockIdx.x;    // 0..63
        const float C = -0.051905126482615036f;          // -log2(10000)/256
        const int f = t;
#pragma unroll
        for (int rep = 0; rep < 6; ++rep) {
            const int r = base + rep * 64;               // 0..383
            unsigned pk = 0;
            if (r <= 256) {
                float ang = (float)r * exp2f(C * (float)f);
                unsigned s = (unsigned)(ushort_t)bf16r(sinf(ang));
                unsigned c = (unsigned)(ushort_t)bf16r(cosf(ang));
                pk = s | (c << 16);
            }
            ((unsigned*)pos)[(size_t)r * 256 + f] = pk;
        }
        return;
    }
    if (widx == 5) {
        const int sub = blockIdx.y * 8 + blockIdx.x;     // 0..63
        // rows [s0, s0+63] of batch b; max row ever read is xl+382 (q-mode)
        {
            const int b = sub >> 5, s0 = (sub & 31) * 64;
            if (s0 >= xlen_p[b] + 383) return;
        }
        const size_t base = (size_t)sub * 32768;
#pragma unroll
        for (int it = 0; it < 8; ++it) {
            const size_t idx = base + (size_t)it * 4096 + (size_t)t * 16;
            const float* src = &x[idx];
            ushort_t t16[16];
#pragma unroll
            for (int u = 0; u < 16; ++u) t16[u] = (ushort_t)bf16r(src[u]);
            *(short8*)&xb16[idx]     = *(short8*)&t16[0];
            *(short8*)&xb16[idx + 8] = *(short8*)&t16[8];
        }
        return;
    }
    if (widx == 6) {
        // column partial sums over 64-row stripes of x (fp32), for vmean
        const int sub = blockIdx.y * 8 + blockIdx.x;     // 0..63
        const int b = sub >> 5, rb = sub & 31;
        const float* src = &x[((size_t)b * 2048 + (size_t)rb * 64) * 512];
        float s0 = 0.f, s1 = 0.f;
        for (int r = 0; r < 64; ++r) {
            s0 += src[(size_t)r * 512 + t];
            s1 += src[(size_t)r * 512 + t + 256];
        }
        xpart[(size_t)sub * 512 + t]       = s0;
        xpart[(size_t)sub * 512 + t + 256] = s1;
        return;
    }
    const float* W = (widx == 0) ? Wq : (widx == 1) ? Wk : (widx == 2) ? Wv : Wkr;
    ushort_t* WT   = (widx == 0) ? WTq : (widx == 1) ? WTk : (widx == 2) ? WTv : WTkr;
    const int k0 = blockIdx.x * 64, n0 = blockIdx.y * 64;
    __shared__ __align__(16) ushort_t T[64][72];
    const int srow = t >> 2, sc0 = (t & 3) * 16;
    const float* src = &W[(size_t)(k0 + srow) * 512 + n0 + sc0];
#pragma unroll
    for (int u = 0; u < 16; ++u) T[sc0 + u][srow] = (ushort_t)bf16r(src[u]);
    __syncthreads();
    ushort_t* dst = &WT[(size_t)(n0 + srow) * 512 + k0 + sc0];
    *(short8*)dst       = *(const short8*)&T[srow][sc0];
    *(short8*)(dst + 8) = *(const short8*)&T[srow][sc0 + 8];
}

// ---------------------------------------------------------------------------
// Kernel 1: fused QKV (+krel +vmean) GEMM.  Grid (32, 25).  R9 structure
// (double-buffered LDS, 1 barrier/K-step).  xlen elision now also on vT
// mode: attn reads vT cols < xlen+63 only (vmean comes from x, not vT).
// by==24: bx<24 krel; bx 24..31 vmean matvec from xpart.
// ---------------------------------------------------------------------------
__global__ __launch_bounds__(256) void qkv_gemm(
    const ushort_t* __restrict__ xb16,
    const ushort_t* __restrict__ WTq, const ushort_t* __restrict__ WTk,
    const ushort_t* __restrict__ WTv,
    const ushort_t* __restrict__ pos, const ushort_t* __restrict__ WTkr,
    const float* __restrict__ b_con, const float* __restrict__ b_rel,
    const float* __restrict__ bv, const int* __restrict__ xlen_p,
    const float* __restrict__ xpart,
    ushort_t* __restrict__ qcon, ushort_t* __restrict__ qrel,
    ushort_t* __restrict__ kout, ushort_t* __restrict__ vT,
    ushort_t* __restrict__ krel, float* __restrict__ vmean)
{
    const int widx = blockIdx.y >> 3;
    const int tid = threadIdx.x, lane = tid & 63, w = tid >> 6;
    const int quad = lane >> 4, l16 = lane & 15;

    __shared__ __align__(16) ushort_t A_lds[2][128][40];
    __shared__ __align__(16) ushort_t B_lds[2][64][40];

    f32x4 acc[2][4];
#pragma unroll
    for (int mt = 0; mt < 2; ++mt)
#pragma unroll
        for (int nt = 0; nt < 4; ++nt) acc[mt][nt] = (f32x4){0.f, 0.f, 0.f, 0.f};

    const int arow = tid >> 1, ak0 = (tid & 1) * 16;
    const int brow = tid >> 2, bk0 = (tid & 3) * 8;

    const ushort_t* Asrc;          // per-mode A row pointer (128 rows x 512)
    const ushort_t* Bsrc;          // per-mode B row pointer (64 rows x 512)

    if (widx < 2) {
        const int m0 = blockIdx.x * 128;
        {
            const int xl = xlen_p[m0 >> 11];
            const int s0 = m0 & 2047;
            if (widx == 0) { if (s0 >= xl + 256) return; }   // q rows dead
            else           { if (s0 >= xl + 63)  return; }   // k rows never staged
        }
        const int n0 = (blockIdx.y & 7) * 64;
        const ushort_t* WT = (widx == 0) ? WTq : WTk;
        Asrc = &xb16[(size_t)(m0 + arow) * 512 + ak0];
        Bsrc = &WT[(size_t)(n0 + brow) * 512 + bk0];
    } else if (widx == 2) {
        const int vb = (blockIdx.y & 7) * 32 + blockIdx.x;   // 0..255
        const int m0d = (vb & 3) * 128;
        const int n0j = (vb >> 2) * 64;
        {
            // attn reads vT cols j <= xlen+62 only; vmean is x-based
            const int xl = xlen_p[n0j >> 11];
            if ((n0j & 2047) >= xl + 63) return;
        }
        Asrc = &WTv[(size_t)(m0d + arow) * 512 + ak0];
        Bsrc = &xb16[(size_t)(n0j + brow) * 512 + bk0];
    } else {
        if (blockIdx.x >= 24) {
            // ---- vmean: vmean[b][d] = mean_x[b] . WTv[d] + bv[d] ----
            float* xm = (float*)A_lds;                       // [2][512] fp32
            for (int idx = tid; idx < 1024; idx += 256) {
                const int bb = idx >> 9, k = idx & 511;
                float s = 0.f;
                for (int p = 0; p < 32; ++p)
                    s += xpart[(size_t)(bb * 32 + p) * 512 + k];
                xm[bb * 512 + k] = s * (1.0f / 2048.0f);
            }
            __syncthreads();
            if (tid < 64) {
                const int d = (blockIdx.x - 24) * 64 + tid;
                const ushort_t* wrow = &WTv[(size_t)d * 512];
                float a0 = 0.f, a1 = 0.f;
                for (int k = 0; k < 512; k += 8) {
                    short8 wv = *(const short8*)(wrow + k);
#pragma unroll
                    for (int u = 0; u < 8; ++u) {
                        const float wf = b2f((ushort_t)wv[u]);
                        a0 += xm[k + u] * wf;
                        a1 += xm[512 + k + u] * wf;
                    }
                }
                const float bvd = bv[d];
                vmean[d]       = a0 + bvd;
                vmean[512 + d] = a1 + bvd;
            }
            return;
        }
        const int m0 = (blockIdx.x >> 3) * 128;
        const int n0 = (blockIdx.x & 7) * 64;
        Asrc = &pos[(size_t)(m0 + arow) * 512 + ak0];
        Bsrc = &WTkr[(size_t)(n0 + brow) * 512 + bk0];
    }

    // ---- shared double-buffered K-loop (identical math order to R6/R9) ----
    {
        short8 pa0 = *(const short8*)Asrc;
        short8 pa1 = *(const short8*)(Asrc + 8);
        short8 pb  = *(const short8*)Bsrc;
        *(short8*)&A_lds[0][arow][ak0]     = pa0;
        *(short8*)&A_lds[0][arow][ak0 + 8] = pa1;
        *(short8*)&B_lds[0][brow][bk0]     = pb;
        pa0 = *(const short8*)(Asrc + 32);
        pa1 = *(const short8*)(Asrc + 40);
        pb  = *(const short8*)(Bsrc + 32);
        __syncthreads();

#pragma unroll 1
        for (int it = 0; it < 16; ++it) {
            const int cur = it & 1;
            if (it < 15) {
                *(short8*)&A_lds[cur ^ 1][arow][ak0]     = pa0;
                *(short8*)&A_lds[cur ^ 1][arow][ak0 + 8] = pa1;
                *(short8*)&B_lds[cur ^ 1][brow][bk0]     = pb;
                if (it < 14) {
                    pa0 = *(const short8*)(Asrc + it * 32 + 64);
                    pa1 = *(const short8*)(Asrc + it * 32 + 72);
                    pb  = *(const short8*)(Bsrc + it * 32 + 64);
                }
            }
            short8 a0 = *(const short8*)&A_lds[cur][w * 32 + l16][quad * 8];
            short8 a1 = *(const short8*)&A_lds[cur][w * 32 + 16 + l16][quad * 8];
#pragma unroll
            for (int nt = 0; nt < 4; ++nt) {
                short8 bb = *(const short8*)&B_lds[cur][nt * 16 + l16][quad * 8];
                acc[0][nt] = __builtin_amdgcn_mfma_f32_16x16x32_bf16(a0, bb, acc[0][nt], 0, 0, 0);
                acc[1][nt] = __builtin_amdgcn_mfma_f32_16x16x32_bf16(a1, bb, acc[1][nt], 0, 0, 0);
            }
            __syncthreads();
        }
    }

    // ---- epilogues ----
    if (widx < 2) {
        const int m0 = blockIdx.x * 128;
        const int n0 = (blockIdx.y & 7) * 64;
#pragma unroll
        for (int nt = 0; nt < 4; ++nt) {
            const int col = n0 + nt * 16 + l16;
            float bc = 0.f, br = 0.f;
            if (widx == 0) { bc = b_con[col]; br = b_rel[col]; }
#pragma unroll
            for (int mt = 0; mt < 2; ++mt) {
#pragma unroll
                for (int reg = 0; reg < 4; ++reg) {
                    const size_t m = (size_t)(m0 + w * 32 + mt * 16 + quad * 4 + reg);
                    const float val = acc[mt][nt][reg];
                    if (widx == 0) {
                        qcon[m * 512 + col] = (ushort_t)bf16r((val + bc) * 0.125f);
                        qrel[m * 512 + col] = (ushort_t)bf16r((val + br) * 0.125f);
                    } else {
                        kout[m * 512 + col] = (ushort_t)bf16r(val);
                    }
                }
            }
        }
    } else if (widx == 2) {
        const int vb = (blockIdx.y & 7) * 32 + blockIdx.x;
        const int m0d = (vb & 3) * 128;
        const int n0j = (vb >> 2) * 64;
        const int b = n0j >> 11;
#pragma unroll
        for (int mt = 0; mt < 2; ++mt) {
#pragma unroll
            for (int reg = 0; reg < 4; ++reg) {
                const int d = m0d + w * 32 + mt * 16 + quad * 4 + reg;  // 0..511
                const int n = d >> 6, dd = d & 63;
                const float bvv = bv[d];
#pragma unroll
                for (int nt = 0; nt < 4; ++nt) {
                    const int s = (n0j + nt * 16 + l16) & 2047;
                    vT[((size_t)((b * NH + n) * 64 + dd)) * 2048 + s] =
                        (ushort_t)bf16r(acc[mt][nt][reg] + bvv);
                }
            }
        }
    } else {
        const int m0 = (blockIdx.x >> 3) * 128;
        const int n0 = (blockIdx.x & 7) * 64;
#pragma unroll
        for (int nt = 0; nt < 4; ++nt) {
            const int col = n0 + nt * 16 + l16;
#pragma unroll
            for (int mt = 0; mt < 2; ++mt)
#pragma unroll
                for (int reg = 0; reg < 4; ++reg) {
                    const size_t m = (size_t)(m0 + w * 32 + mt * 16 + quad * 4 + reg);
                    krel[m * 512 + col] = (ushort_t)bf16r(acc[mt][nt][reg]);
                }
        }
    }
}

// ---------------------------------------------------------------------------
// Kernel 2: banded attention with FUSED rel-energy.  R11 structure, plus:
// first-chunk k/vT global loads and q-con fragment loads are HOISTED before
// the RG phase so their HBM latency hides under RG's MFMA work.
// LDS 60.4 KB -> 2 blocks/CU == full co-residency for 512 blocks.
// ---------------------------------------------------------------------------
__global__ __launch_bounds__(256) void attn_kernel(
    const ushort_t* __restrict__ qcon, const ushort_t* __restrict__ qrel,
    const ushort_t* __restrict__ kbuf, const ushort_t* __restrict__ vT,
    const ushort_t* __restrict__ krel, const float* __restrict__ vmean,
    const int* __restrict__ xlen_p, float* __restrict__ out)
{
    const int bx = blockIdx.x;
    const int tile = ((bx & 7) << 2) | (bx >> 3);   // XCD swizzle, 32 tiles
    const int n = blockIdx.y, b = blockIdx.z;
    const int i0 = tile * 64;
    const int tid = threadIdx.x, lane = tid & 63, w = tid >> 6;
    const int quad = lane >> 4, l16 = lane & 15;
    const int xlen = xlen_p[b];

    // ---- dead-tile fast path: every row fully masked -> uniform softmax ----
    if (i0 >= xlen + 256) {
        const int row = tid >> 2, cf = (tid & 3) * 16;
        const float* vm = &vmean[(size_t)b * 512 + n * 64 + cf];
        float* dst = &out[((size_t)b * S_ + i0 + row) * 512 + n * 64 + cf];
#pragma unroll
        for (int u = 0; u < 16; u += 4)
            *(float4*)&dst[u] = *(const float4*)&vm[u];
        return;
    }
    int nchunk = (xlen - i0 + 256 + 63) >> 6;
    if (nchunk > 5) nchunk = 5;
    const int c0 = (i0 < 256) ? ((256 - i0) >> 6) : 0;   // first chunk with jc0 >= 0

    __shared__ __align__(16) ushort_t k_lds[64][LP];     // krel (RG) then k
    __shared__ __align__(16) ushort_t vT_lds[64][LP];
    __shared__ __align__(16) ushort_t R_lds[64][RP];     // R panel, overlaid by p

    const int srow = tid >> 2, sc0 = (tid & 3) * 16;     // 64 rows x 64 cols staging
    const size_t vTbase = (size_t)((b * NH + n) * 64) * 2048;

    short8 kr[2], vr[2], kn[2], vn[2];

    auto issue = [&](int c, short8* kd, short8* vd) {
        const int jc0 = i0 - 256 + c * 64;              // >= 0 for c >= c0
        const ushort_t* ks = &kbuf[((size_t)b * S_ + jc0 + srow) * 512 + n * 64 + sc0];
        kd[0] = *(const short8*)ks;
        kd[1] = *(const short8*)(ks + 8);
        const ushort_t* vs = &vT[vTbase + (size_t)srow * 2048 + jc0 + sc0];
        vd[0] = *(const short8*)vs;
        vd[1] = *(const short8*)(vs + 8);
    };

    // ---- hoisted prefetches: independent of RG; latency hides under RG ----
    const ushort_t* qc = &qcon[((size_t)b * S_ + i0 + w * 16 + l16) * 512 + n * 64 + quad * 8];
    const short8 aq0 = *(const short8*)qc;
    const short8 aq1 = *(const short8*)(qc + 32);
    issue(c0, kr, vr);

    // ---- RG phase: R_lds[row][row+256-r] = qrel[i0+row] . krel[r] ----
    {
        const ushort_t* qr = &qrel[((size_t)b * S_ + i0 + w * 16 + l16) * 512 + n * 64 + quad * 8];
        const short8 ar0 = *(const short8*)qr;
        const short8 ar1 = *(const short8*)(qr + 32);
        const int rlim = (i0 + 63 < 256) ? i0 + 63 : 256;   // max live r
#pragma unroll 1
        for (int rc = 0; rc <= (rlim >> 6); ++rc) {
            const ushort_t* ks = &krel[(size_t)(rc * 64 + srow) * 512 + n * 64 + sc0];
            short8 s0v = *(const short8*)ks;
            short8 s1v = *(const short8*)(ks + 8);
            __syncthreads();          // prev chunk's k_lds reads done
            *(short8*)&k_lds[srow][sc0]     = s0v;
            *(short8*)&k_lds[srow][sc0 + 8] = s1v;
            __syncthreads();
#pragma unroll
            for (int nt = 0; nt < 4; ++nt) {
                if (rc * 64 + nt * 16 <= rlim) {           // block-uniform
                    short8 b0 = *(const short8*)&k_lds[nt * 16 + l16][quad * 8];
                    short8 b1 = *(const short8*)&k_lds[nt * 16 + l16][quad * 8 + 32];
                    f32x4 s = (f32x4){0.f, 0.f, 0.f, 0.f};
                    s = __builtin_amdgcn_mfma_f32_16x16x32_bf16(ar0, b0, s, 0, 0, 0);
                    s = __builtin_amdgcn_mfma_f32_16x16x32_bf16(ar1, b1, s, 0, 0, 0);
                    const int r = rc * 64 + nt * 16 + l16;
#pragma unroll
                    for (int reg = 0; reg < 4; ++reg) {
                        const int rowq = w * 16 + quad * 4 + reg;   // wave-local
                        if (r <= 256) R_lds[rowq][rowq + 256 - r] = (ushort_t)bf16r(s[reg]);
                    }
                }
            }
        }
    }

    f32x4 Oa[4];
#pragma unroll
    for (int nt = 0; nt < 4; ++nt) Oa[nt] = (f32x4){0.f, 0.f, 0.f, 0.f};
    float lpart[4] = {};

#pragma unroll 1
    for (int c = c0; c < nchunk; ++c) {
        const int jc0 = i0 - 256 + c * 64;
        __syncthreads();   // prev-chunk reads of k/vT done (RG's k_lds reads on c==c0)
        *(short8*)&k_lds[srow][sc0]      = kr[0];
        *(short8*)&k_lds[srow][sc0 + 8]  = kr[1];
        *(short8*)&vT_lds[srow][sc0]     = vr[0];
        *(short8*)&vT_lds[srow][sc0 + 8] = vr[1];
        if (c + 1 < nchunk) issue(c + 1, kn, vn);
        __syncthreads();

        // ---- QK ----
        f32x4 Sacc[4];
#pragma unroll
        for (int jt = 0; jt < 4; ++jt) {
            short8 bk0 = *(const short8*)&k_lds[jt * 16 + l16][quad * 8];
            short8 bk1 = *(const short8*)&k_lds[jt * 16 + l16][quad * 8 + 32];
            f32x4 s = (f32x4){0.f, 0.f, 0.f, 0.f};
            s = __builtin_amdgcn_mfma_f32_16x16x32_bf16(aq0, bk0, s, 0, 0, 0);
            s = __builtin_amdgcn_mfma_f32_16x16x32_bf16(aq1, bk1, s, 0, 0, 0);
            Sacc[jt] = s;
        }

        // ---- mask + rel bias + exp; p overwrites R_lds slot (wave-local) ----
#pragma unroll
        for (int jt = 0; jt < 4; ++jt) {
#pragma unroll
            for (int reg = 0; reg < 4; ++reg) {
                const int row = w * 16 + quad * 4 + reg;
                const int i = i0 + row;
                const int j = jc0 + jt * 16 + l16;
                const int r = i - j;
                const bool valid = (j < xlen) && (r >= 0) && (r <= 256);
                float rvv = b2f(R_lds[row][c * 64 + jt * 16 + l16]);
                float e = valid ? __expf(Sacc[jt][reg] + rvv) : 0.f;
                lpart[reg] += e;
                R_lds[row][c * 64 + jt * 16 + l16] = (ushort_t)bf16r(e);
            }
        }
        // no barrier: p rows are wave-local (written+read by the same wave)

        // ---- PV (p read from R_lds overlay) ----
        short8 ap0 = *(const short8*)&R_lds[w * 16 + l16][c * 64 + quad * 8];
        short8 ap1 = *(const short8*)&R_lds[w * 16 + l16][c * 64 + quad * 8 + 32];
#pragma unroll
        for (int nt = 0; nt < 4; ++nt) {
            short8 bv0 = *(const short8*)&vT_lds[nt * 16 + l16][quad * 8];
            short8 bv1 = *(const short8*)&vT_lds[nt * 16 + l16][quad * 8 + 32];
            Oa[nt] = __builtin_amdgcn_mfma_f32_16x16x32_bf16(ap0, bv0, Oa[nt], 0, 0, 0);
            Oa[nt] = __builtin_amdgcn_mfma_f32_16x16x32_bf16(ap1, bv1, Oa[nt], 0, 0, 0);
        }

        // ---- rotate register sets ----
        kr[0] = kn[0]; kr[1] = kn[1];
        vr[0] = vn[0]; vr[1] = vn[1];
    }

#pragma unroll
    for (int reg = 0; reg < 4; ++reg) {
#pragma unroll
        for (int off = 1; off < 16; off <<= 1)
            lpart[reg] += __shfl_xor(lpart[reg], off, 64);
    }

#pragma unroll
    for (int reg = 0; reg < 4; ++reg) {
        const int i = i0 + w * 16 + quad * 4 + reg;
        const bool dead = (i >= xlen + 256);
        const float linv = 1.0f / lpart[reg];
#pragma unroll
        for (int nt = 0; nt < 4; ++nt) {
            const int d = n * 64 + nt * 16 + l16;
            float val = dead ? vmean[(size_t)b * 512 + d] : Oa[nt][reg] * linv;
            out[((size_t)b * S_ + i) * 512 + d] = val;
        }
    }
}

// ---------------------------------------------------------------------------
extern "C" void kernel_launch(void* const* d_in, const int* in_sizes, int n_in,
                              void* d_out, int out_size, void* d_ws, size_t ws_size,
                              hipStream_t stream) {
    const float* x     = (const float*)d_in[0];
    const float* Wq    = (const float*)d_in[1];
    const float* b_con = (const float*)d_in[2];
    const float* b_rel = (const float*)d_in[3];
    const float* Wk    = (const float*)d_in[4];
    const float* Wkr   = (const float*)d_in[5];
    const float* Wv    = (const float*)d_in[6];
    const float* bv    = (const float*)d_in[7];
    const int*   xlen  = (const int*)d_in[8];
    float* out = (float*)d_out;

    float* ws = (float*)d_ws;
    float* vmean = ws;                       // 1024 fp32
    float* xpart = vmean + 1024;             // 64*512 fp32
    ushort_t* ub   = (ushort_t*)(xpart + 32768);
    ushort_t* qcon = ub;                     // 2048*2*512 bf16 each
    ushort_t* kbuf = qcon + 2097152;
    ushort_t* vT   = kbuf + 2097152;         // 1024 x 2048 bf16
    ushort_t* qrel = vT   + 2097152;
    ushort_t* xb16 = qrel + 2097152;         // 4096*512 bf16
    ushort_t* krel = xb16 + 2097152;         // 384*512 bf16
    ushort_t* pos  = krel + 196608;          // 384*512 bf16
    ushort_t* WTq  = pos  + 196608;          // 512*512 bf16 each
    ushort_t* WTk  = WTq + 262144;
    ushort_t* WTv  = WTk + 262144;
    ushort_t* WTkr = WTv + 262144;

    prep_kernel<<<dim3(8, 8, 7), 256, 0, stream>>>(x, Wq, Wk, Wv, Wkr, xlen,
                                                   WTq, WTk, WTv, WTkr, pos, xb16,
                                                   xpart);
    qkv_gemm<<<dim3(32, 25), 256, 0, stream>>>(xb16, WTq, WTk, WTv, pos, WTkr,
                                               b_con, b_rel, bv, xlen, xpart,
                                               qcon, qrel, kbuf, vT, krel, vmean);
    attn_kernel<<<dim3(32, 8, 2), 256, 0, stream>>>(qcon, qrel, kbuf, vT, krel,
                                                    vmean, xlen, out);
}